// Round 1
// baseline (92.799 us; speedup 1.0000x reference)
//
#include <hip/hip_runtime.h>
#include <hip/hip_bf16.h>

#define D_DIM 256
#define TEMP 0.2f
// ZSCALE = sqrt(log2(e)/TEMP): fold 1/(T*ln2) into z so epilogue is exp2(acc)
#define ZSCALE 2.6857913f

typedef __bf16 bf16x8 __attribute__((ext_vector_type(8)));
typedef float f32x4 __attribute__((ext_vector_type(4)));

typedef const __attribute__((address_space(1))) void* gptr_t;
typedef __attribute__((address_space(3))) void* lptr_t;

// ---------------- kernel 1: normalize + positives ----------------
// One block (256 threads) per row pair b. Computes |ei_b|, |ej_b|, ei_b.ej_b in fp32,
// stores z' = normalize(e)*ZSCALE as bf16 into zbuf[0..B) and zbuf[B..2B), pos[b] = cos sim.
__global__ __launch_bounds__(256) void nt_normalize(
    const float* __restrict__ ei, const float* __restrict__ ej,
    ushort* __restrict__ z, float* __restrict__ pos, int B) {
  int b = blockIdx.x;
  int d = threadIdx.x;
  float xi = ei[(size_t)b * D_DIM + d];
  float xj = ej[(size_t)b * D_DIM + d];
  float si = xi * xi, sj = xj * xj, sij = xi * xj;
  for (int off = 1; off < 64; off <<= 1) {
    si  += __shfl_xor(si, off);
    sj  += __shfl_xor(sj, off);
    sij += __shfl_xor(sij, off);
  }
  __shared__ float red[3][4];
  int wv = threadIdx.x >> 6, lane = threadIdx.x & 63;
  if (lane == 0) { red[0][wv] = si; red[1][wv] = sj; red[2][wv] = sij; }
  __syncthreads();
  si  = red[0][0] + red[0][1] + red[0][2] + red[0][3];
  sj  = red[1][0] + red[1][1] + red[1][2] + red[1][3];
  sij = red[2][0] + red[2][1] + red[2][2] + red[2][3];
  float ri = rsqrtf(si), rj = rsqrtf(sj);
  __hip_bfloat16 zi = __float2bfloat16(xi * ri * ZSCALE);
  __hip_bfloat16 zj = __float2bfloat16(xj * rj * ZSCALE);
  z[(size_t)b * D_DIM + d]       = *reinterpret_cast<ushort*>(&zi);
  z[(size_t)(B + b) * D_DIM + d] = *reinterpret_cast<ushort*>(&zj);
  if (threadIdx.x == 0) pos[b] = sij * ri * rj;
}

// ---------------- kernel 2: fused GEMM + exp2 + row partial sums ----------------
// Tile 128x128, 4 waves (each 64x64 = 4x4 frags of 16x16x32 bf16 MFMA), BK=64.
// partial[ct*2+wc][row] = sum over this tile's 64 cols of exp2(sim'), diag excluded.
#define BM 128
#define BK 64

__global__ __launch_bounds__(256) void nt_gemm_rowsum(
    const ushort* __restrict__ z, float* __restrict__ partial, int N) {
  int rt = blockIdx.y, ct = blockIdx.x;
  __shared__ __align__(16) ushort As[BM * BK];
  __shared__ __align__(16) ushort Bs[BM * BK];
  int t = threadIdx.x;
  int lane = t & 63;
  int wv = t >> 6;
  int wr = wv >> 1, wc = wv & 1;

  f32x4 acc[4][4];
#pragma unroll
  for (int m = 0; m < 4; ++m)
#pragma unroll
    for (int n = 0; n < 4; ++n) acc[m][n] = f32x4{0.f, 0.f, 0.f, 0.f};

  const char* zb = (const char*)z;  // row stride = 512 bytes (256 bf16)

#pragma unroll
  for (int kt = 0; kt < D_DIM / BK; ++kt) {
    // stage A (rows rt*128..) and B (rows ct*128..), 16KB each, 16B/lane chunks
#pragma unroll
    for (int p = 0; p < 4; ++p) {
      int chunk = p * 256 + t;          // 16-byte chunk id, 0..1023
      int row = chunk >> 3;             // 8 chunks per 128-byte k-slice row
      int cb  = (chunk & 7) << 4;       // byte offset within k-slice
      const char* ga = zb + (size_t)(rt * BM + row) * 512 + kt * 128 + cb;
      const char* gb = zb + (size_t)(ct * BM + row) * 512 + kt * 128 + cb;
      __builtin_amdgcn_global_load_lds((gptr_t)ga, (lptr_t)(As + chunk * 8), 16, 0, 0);
      __builtin_amdgcn_global_load_lds((gptr_t)gb, (lptr_t)(Bs + chunk * 8), 16, 0, 0);
    }
    __syncthreads();
#pragma unroll
    for (int ks = 0; ks < BK / 32; ++ks) {
      bf16x8 af[4], bfr[4];
      int k = ks * 32 + (lane >> 4) * 8;
#pragma unroll
      for (int m = 0; m < 4; ++m) {
        int r = wr * 64 + m * 16 + (lane & 15);
        af[m] = *reinterpret_cast<const bf16x8*>(&As[r * BK + k]);
      }
#pragma unroll
      for (int n = 0; n < 4; ++n) {
        int r = wc * 64 + n * 16 + (lane & 15);
        bfr[n] = *reinterpret_cast<const bf16x8*>(&Bs[r * BK + k]);
      }
#pragma unroll
      for (int m = 0; m < 4; ++m)
#pragma unroll
        for (int n = 0; n < 4; ++n)
          acc[m][n] = __builtin_amdgcn_mfma_f32_16x16x32_bf16(af[m], bfr[n], acc[m][n], 0, 0, 0);
    }
    __syncthreads();
  }

  // epilogue: exp2, mask diagonal, per-row sum over this wave's 64 cols
  int rbase = rt * BM + wr * 64;
  int cbase = ct * BM + wc * 64 + (lane & 15);
  int pcol = ct * 2 + wc;
#pragma unroll
  for (int m = 0; m < 4; ++m) {
#pragma unroll
    for (int j = 0; j < 4; ++j) {
      int rowg = rbase + m * 16 + (lane >> 4) * 4 + j;
      float rs = 0.f;
#pragma unroll
      for (int n = 0; n < 4; ++n) {
        int colg = cbase + n * 16;
        float e = exp2f(acc[m][n][j]);
        rs += (rowg == colg) ? 0.f : e;
      }
      rs += __shfl_xor(rs, 1);
      rs += __shfl_xor(rs, 2);
      rs += __shfl_xor(rs, 4);
      rs += __shfl_xor(rs, 8);
      if ((lane & 15) == 0) partial[(size_t)pcol * N + rowg] = rs;
    }
  }
}

// ---------------- kernel 3: per-row finish ----------------
__global__ __launch_bounds__(256) void nt_rowfinish(
    const float* __restrict__ partial, const float* __restrict__ pos,
    float* __restrict__ rowfinal, int N, int B) {
  int r = blockIdx.x * blockDim.x + threadIdx.x;
  if (r >= N) return;
  float s = 0.f;
#pragma unroll 8
  for (int p = 0; p < 128; ++p) s += partial[(size_t)p * N + r];
  float pv = pos[r < B ? r : r - B];
  rowfinal[r] = logf(s) - pv * (1.0f / TEMP);
}

// ---------------- kernel 4: final scalar reduce ----------------
__global__ __launch_bounds__(256) void nt_final(
    const float* __restrict__ rowfinal, float* __restrict__ out, int N) {
  float s = 0.f;
  for (int i = threadIdx.x; i < N; i += 256) s += rowfinal[i];
  for (int off = 1; off < 64; off <<= 1) s += __shfl_xor(s, off);
  __shared__ float red[4];
  int wv = threadIdx.x >> 6, lane = threadIdx.x & 63;
  if (lane == 0) red[wv] = s;
  __syncthreads();
  if (threadIdx.x == 0) out[0] = (red[0] + red[1] + red[2] + red[3]) / (float)N;
}

extern "C" void kernel_launch(void* const* d_in, const int* in_sizes, int n_in,
                              void* d_out, int out_size, void* d_ws, size_t ws_size,
                              hipStream_t stream) {
  const float* ei = (const float*)d_in[0];
  const float* ej = (const float*)d_in[1];
  int B = in_sizes[0] / D_DIM;  // 4096
  int N = 2 * B;                // 8192

  char* ws = (char*)d_ws;
  ushort* z      = (ushort*)ws;                                   // N*256*2  = 4 MB
  float* partial = (float*)(ws + (size_t)N * D_DIM * 2);          // 128*N*4  = 4 MB
  float* pos     = (float*)(ws + (size_t)N * D_DIM * 2 + (size_t)128 * N * 4);
  float* rowfinal = pos + B;
  float* out = (float*)d_out;

  nt_normalize<<<B, 256, 0, stream>>>(ei, ej, z, pos, B);
  dim3 grid(N / 128, N / 128);
  nt_gemm_rowsum<<<grid, 256, 0, stream>>>(z, partial, N);
  nt_rowfinish<<<(N + 255) / 256, 256, 0, stream>>>(partial, pos, rowfinal, N, B);
  nt_final<<<1, 256, 0, stream>>>(rowfinal, out, N);
}

// Round 2
// 62.816 us; speedup vs baseline: 1.4773x; 1.4773x over previous
//
#include <hip/hip_runtime.h>
#include <hip/hip_bf16.h>

#define D_DIM 256
#define TEMP 0.2f
// ZSCALE = sqrt(log2(e)/TEMP): fold 1/(T*ln2) into z so epilogue is exp2(acc)
#define ZSCALE 2.6857913f

typedef __bf16 bf16x8 __attribute__((ext_vector_type(8)));
typedef float f32x4 __attribute__((ext_vector_type(4)));

typedef const __attribute__((address_space(1))) void* gptr_t;
typedef __attribute__((address_space(3))) void* lptr_t;

// ---------------- kernel 1: normalize + positives ----------------
__global__ __launch_bounds__(256) void nt_normalize(
    const float* __restrict__ ei, const float* __restrict__ ej,
    ushort* __restrict__ z, float* __restrict__ pos, int B) {
  int b = blockIdx.x;
  int d = threadIdx.x;
  float xi = ei[(size_t)b * D_DIM + d];
  float xj = ej[(size_t)b * D_DIM + d];
  float si = xi * xi, sj = xj * xj, sij = xi * xj;
  for (int off = 1; off < 64; off <<= 1) {
    si  += __shfl_xor(si, off);
    sj  += __shfl_xor(sj, off);
    sij += __shfl_xor(sij, off);
  }
  __shared__ float red[3][4];
  int wv = threadIdx.x >> 6, lane = threadIdx.x & 63;
  if (lane == 0) { red[0][wv] = si; red[1][wv] = sj; red[2][wv] = sij; }
  __syncthreads();
  si  = red[0][0] + red[0][1] + red[0][2] + red[0][3];
  sj  = red[1][0] + red[1][1] + red[1][2] + red[1][3];
  sij = red[2][0] + red[2][1] + red[2][2] + red[2][3];
  float ri = rsqrtf(si), rj = rsqrtf(sj);
  __hip_bfloat16 zi = __float2bfloat16(xi * ri * ZSCALE);
  __hip_bfloat16 zj = __float2bfloat16(xj * rj * ZSCALE);
  z[(size_t)b * D_DIM + d]       = *reinterpret_cast<ushort*>(&zi);
  z[(size_t)(B + b) * D_DIM + d] = *reinterpret_cast<ushort*>(&zj);
  if (threadIdx.x == 0) pos[b] = sij * ri * rj;
}

// ---------------- kernel 2: triangular fused GEMM + exp2 + row/col sums ----
// Only tiles ct>=rt (symmetry: exp(sim) symmetric => col-sums of a tile are
// row-sums of its transpose). Tile 128x128, BK=128 (2 K-steps), 4 waves each
// owning a 64x64 sub-tile. LDS 64KB -> 2 blocks/CU. XOR swizzle
// (byte ^= (row&7)<<4) applied on the global SOURCE for global_load_lds
// (LDS dest linear) and on the ds_read address (both-sides rule).
// Slots: row-sums of tile(rt,ct) -> partial[2*ct+wc][row];
//        col-sums (rt<ct only)   -> partial[2*rt+wr][col].
// Every (row, slot) in [0,N)x[0,128) is written exactly once.
#define BM 128
#define BK 128
#define TGRID 64  // N / BM

__global__ __launch_bounds__(256, 2) void nt_gemm_rowsum(
    const ushort* __restrict__ z, float* __restrict__ partial, int N) {
  // triangular decode: block k -> (rt, ct) with rt <= ct
  int k = blockIdx.x;
  int rt = (int)((2 * TGRID + 1 -
                  sqrtf((float)((2 * TGRID + 1) * (2 * TGRID + 1) - 8 * k))) * 0.5f);
  if (rt > TGRID - 1) rt = TGRID - 1;
  if (rt < 0) rt = 0;
  while (rt > 0 && k < rt * (2 * TGRID - rt + 1) / 2) --rt;
  while (k >= (rt + 1) * (2 * TGRID - rt) / 2) ++rt;
  int ct = rt + (k - rt * (2 * TGRID - rt + 1) / 2);

  __shared__ __align__(16) ushort As[BM * BK];
  __shared__ __align__(16) ushort Bs[BM * BK];
  int t = threadIdx.x;
  int lane = t & 63;
  int wv = t >> 6;
  int wr = wv >> 1, wc = wv & 1;

  f32x4 acc[4][4];
#pragma unroll
  for (int m = 0; m < 4; ++m)
#pragma unroll
    for (int n = 0; n < 4; ++n) acc[m][n] = f32x4{0.f, 0.f, 0.f, 0.f};

  const char* zb = (const char*)z;  // row stride 512 B (256 bf16)
  char* asb = (char*)As;
  char* bsb = (char*)Bs;

#pragma unroll
  for (int kt = 0; kt < D_DIM / BK; ++kt) {
    // stage A rows rt*128.. and B rows ct*128..; 32KB each; 16B chunks.
    // LDS physical chunk (row, c) holds logical chunk c ^ (row&7) -> source
    // byte = row*512 + kt*256 + (c ^ (row&7))*16, dest = linear chunk*16.
#pragma unroll
    for (int p = 0; p < 8; ++p) {
      int chunk = p * 256 + t;          // 0..2047
      int row = chunk >> 4;             // 16 chunks per 256B k-slice row
      int c = chunk & 15;
      int cl = c ^ (row & 7);
      const char* ga = zb + (size_t)(rt * BM + row) * 512 + kt * 256 + cl * 16;
      const char* gb = zb + (size_t)(ct * BM + row) * 512 + kt * 256 + cl * 16;
      __builtin_amdgcn_global_load_lds((gptr_t)ga, (lptr_t)(asb + chunk * 16), 16, 0, 0);
      __builtin_amdgcn_global_load_lds((gptr_t)gb, (lptr_t)(bsb + chunk * 16), 16, 0, 0);
    }
    __syncthreads();
#pragma unroll
    for (int ks = 0; ks < BK / 32; ++ks) {
      bf16x8 af[4], bfr[4];
      int kbyte = ks * 64 + (lane >> 4) * 16;
#pragma unroll
      for (int m = 0; m < 4; ++m) {
        int r = wr * 64 + m * 16 + (lane & 15);
        int addr = ((r << 8) + kbyte) ^ ((r & 7) << 4);
        af[m] = *reinterpret_cast<const bf16x8*>(asb + addr);
      }
#pragma unroll
      for (int n = 0; n < 4; ++n) {
        int r = wc * 64 + n * 16 + (lane & 15);
        int addr = ((r << 8) + kbyte) ^ ((r & 7) << 4);
        bfr[n] = *reinterpret_cast<const bf16x8*>(bsb + addr);
      }
#pragma unroll
      for (int m = 0; m < 4; ++m)
#pragma unroll
        for (int n = 0; n < 4; ++n)
          acc[m][n] = __builtin_amdgcn_mfma_f32_16x16x32_bf16(af[m], bfr[n], acc[m][n], 0, 0, 0);
    }
    __syncthreads();
  }

  // epilogue: exp2 in place (diag masked on diagonal tiles), then row sums
  // (all tiles) and col sums (off-diagonal tiles only).
  bool isdiag = (rt == ct);
  int rbase = rt * BM + wr * 64;
  int cbase = ct * BM + wc * 64 + (lane & 15);
#pragma unroll
  for (int m = 0; m < 4; ++m)
#pragma unroll
    for (int n = 0; n < 4; ++n)
#pragma unroll
      for (int j = 0; j < 4; ++j) {
        int rowg = rbase + m * 16 + (lane >> 4) * 4 + j;
        int colg = cbase + n * 16;
        float e = exp2f(acc[m][n][j]);
        acc[m][n][j] = (isdiag && rowg == colg) ? 0.f : e;
      }
  // row sums -> slot 2*ct + wc
#pragma unroll
  for (int m = 0; m < 4; ++m)
#pragma unroll
    for (int j = 0; j < 4; ++j) {
      float rs = acc[m][0][j] + acc[m][1][j] + acc[m][2][j] + acc[m][3][j];
      rs += __shfl_xor(rs, 1);
      rs += __shfl_xor(rs, 2);
      rs += __shfl_xor(rs, 4);
      rs += __shfl_xor(rs, 8);
      if ((lane & 15) == 0) {
        int rowg = rbase + m * 16 + (lane >> 4) * 4 + j;
        partial[(size_t)(2 * ct + wc) * N + rowg] = rs;
      }
    }
  // col sums -> slot 2*rt + wr (off-diagonal only)
  if (!isdiag) {
#pragma unroll
    for (int n = 0; n < 4; ++n) {
      float cs = 0.f;
#pragma unroll
      for (int m = 0; m < 4; ++m)
#pragma unroll
        for (int j = 0; j < 4; ++j) cs += acc[m][n][j];
      cs += __shfl_xor(cs, 16);
      cs += __shfl_xor(cs, 32);
      if ((lane >> 4) == 0) {
        int colg = cbase + n * 16;
        partial[(size_t)(2 * rt + wr) * N + colg] = cs;
      }
    }
  }
}

// ---------------- kernel 3: per-row finish ----------------
__global__ __launch_bounds__(256) void nt_rowfinish(
    const float* __restrict__ partial, const float* __restrict__ pos,
    float* __restrict__ rowfinal, int N, int B) {
  int r = blockIdx.x * blockDim.x + threadIdx.x;
  if (r >= N) return;
  float s = 0.f;
#pragma unroll 8
  for (int p = 0; p < 128; ++p) s += partial[(size_t)p * N + r];
  float pv = pos[r < B ? r : r - B];
  rowfinal[r] = logf(s) - pv * (1.0f / TEMP);
}

// ---------------- kernel 4: final scalar reduce ----------------
__global__ __launch_bounds__(1024) void nt_final(
    const float* __restrict__ rowfinal, float* __restrict__ out, int N) {
  float s = 0.f;
  for (int i = threadIdx.x; i < N; i += 1024) s += rowfinal[i];
  for (int off = 1; off < 64; off <<= 1) s += __shfl_xor(s, off);
  __shared__ float red[16];
  int wv = threadIdx.x >> 6, lane = threadIdx.x & 63;
  if (lane == 0) red[wv] = s;
  __syncthreads();
  if (threadIdx.x == 0) {
    float tot = 0.f;
#pragma unroll
    for (int i = 0; i < 16; ++i) tot += red[i];
    out[0] = tot / (float)N;
  }
}

extern "C" void kernel_launch(void* const* d_in, const int* in_sizes, int n_in,
                              void* d_out, int out_size, void* d_ws, size_t ws_size,
                              hipStream_t stream) {
  const float* ei = (const float*)d_in[0];
  const float* ej = (const float*)d_in[1];
  int B = in_sizes[0] / D_DIM;  // 4096
  int N = 2 * B;                // 8192

  char* ws = (char*)d_ws;
  ushort* z      = (ushort*)ws;                                   // N*256*2  = 4 MB
  float* partial = (float*)(ws + (size_t)N * D_DIM * 2);          // 128*N*4  = 4 MB
  float* pos     = (float*)(ws + (size_t)N * D_DIM * 2 + (size_t)128 * N * 4);
  float* rowfinal = pos + B;
  float* out = (float*)d_out;

  nt_normalize<<<B, 256, 0, stream>>>(ei, ej, z, pos, B);
  int nblocks = TGRID * (TGRID + 1) / 2;  // 2080 triangular tiles
  nt_gemm_rowsum<<<nblocks, 256, 0, stream>>>(z, partial, N);
  nt_rowfinish<<<(N + 255) / 256, 256, 0, stream>>>(partial, pos, rowfinal, N, B);
  nt_final<<<1, 1024, 0, stream>>>(rowfinal, out, N);
}